// Round 8
// baseline (248.616 us; speedup 1.0000x reference)
//
#include <hip/hip_runtime.h>
#include <hip/hip_bf16.h>
#include <math.h>

// B=16, T=1024, C=768, H=128
#define NTOK   16384     // B*T
#define NEMBD  768
#define HDIM   128

// ===========================================================================
// MEASUREMENT ROUND (R8): qkv body x3, attn body x5 (idempotent reps, base
// pointers laundered per-rep to block cross-rep CSE). Surfaces both kernels
// above the 42us poison-fills in the rocprof top-5 to get REAL counters.
// Structure otherwise byte-identical to R7. Revert reps next round.
// ===========================================================================

typedef __attribute__((ext_vector_type(8)))  short short8;
typedef __attribute__((ext_vector_type(16))) float floatx16;

#define MFMA32(a,b,c) __builtin_amdgcn_mfma_f32_32x32x16_bf16(a,b,c,0,0,0)

__device__ __forceinline__ unsigned short f2bf(float f) {
    unsigned u = __float_as_uint(f);
    u += 0x7fff + ((u >> 16) & 1);          // RNE
    return (unsigned short)(u >> 16);
}
// RNE pack of 2 floats -> 2 bf16 (low = a, high = b). Scalar-cast form:
// compiler lowers to one v_cvt_pk_bf16_f32 AND can schedule it.
__device__ __forceinline__ unsigned pack2(float a, float b) {
    __hip_bfloat162 h2 = __float22bfloat162_rn(make_float2(a, b));
    union { __hip_bfloat162 h; unsigned u; } c; c.h = h2;
    return c.u;
}
// truncating bf16 pack: one v_perm_b32. D = [hi16(b) | hi16(a)]
__device__ __forceinline__ unsigned pack2_trunc(float a, float b) {
    return __builtin_amdgcn_perm(__float_as_uint(b), __float_as_uint(a),
                                 0x07060302u);
}

// ---------------------------------------------------------------------------
// Kernel 0: W -> bf16 in MFMA FRAGMENT ORDER. (UNCHANGED from R7.)
// ---------------------------------------------------------------------------
__global__ __launch_bounds__(256) void prep_w(
    const float* __restrict__ Wk, const float* __restrict__ Wq,
    const float* __restrict__ Wv, unsigned short* __restrict__ wt)
{
    __shared__ float T[64 * 65];               // [dloc][c], pad 65

    const int tid = threadIdx.x;
    const int bw  = blockIdx.x / 24;
    const int rem = blockIdx.x % 24;
    const int ct  = rem >> 1, dh = rem & 1;
    const int c0  = ct * 64;
    const float* W = (bw == 0) ? Wk : ((bw == 1) ? Wq : Wv);
    const float scale = (bw == 1)
        ? (0.03608439182435161f * 1.4426950408889634f) : 1.0f;

    #pragma unroll
    for (int pass = 0; pass < 4; ++pass) {
        int idx = pass * 256 + tid;            // 0..1023
        int c  = idx >> 4;                     // 0..63
        int d4 = idx & 15;                     // float4 idx within d-half
        float4 v = ((const float4*)W)[(size_t)(c0 + c) * 32 + dh * 16 + d4];
        v.x *= scale; v.y *= scale; v.z *= scale; v.w *= scale;
        T[(d4 * 4 + 0) * 65 + c] = v.x;
        T[(d4 * 4 + 1) * 65 + c] = v.y;
        T[(d4 * 4 + 2) * 65 + c] = v.z;
        T[(d4 * 4 + 3) * 65 + c] = v.w;
    }
    __syncthreads();

    #pragma unroll
    for (int pass = 0; pass < 2; ++pass) {
        int idx  = pass * 256 + tid;           // 0..511
        int dloc = idx >> 3;                   // 0..63
        int c8   = idx & 7;                    // 8-col chunk within c-tile
        const float* row = &T[dloc * 65 + c8 * 8];
        uint4 u = make_uint4(pack2(row[0], row[1]), pack2(row[2], row[3]),
                             pack2(row[4], row[5]), pack2(row[6], row[7]));
        int kc    = ct * 8 + c8;               // global 8-col chunk 0..95
        int ksl   = kc >> 1, hb = kc & 1;
        int dglob = dh * 64 + dloc;
        int nt    = dglob >> 5;
        int lanef = (dglob & 31) + 32 * hb;
        ((uint4*)wt)[(size_t)((bw * 4 + nt) * 48 + ksl) * 64 + lanef] = u;
    }
}

// ---------------------------------------------------------------------------
// Kernel 1: R7 structure (B direct from global, A-only LDS dbuf), body
// repeated x3 for measurement. Rep discrimination:
//   dur ~42-50us  -> reps 2-3 L3-warm-fast => cold-HBM-bound, qkv at floor.
//   dur ~75-90us  -> warm no faster => structure-bound; read pipe counters.
// ---------------------------------------------------------------------------
__global__ __launch_bounds__(512) void qkv_fused(
    const float* __restrict__ x, const unsigned short* __restrict__ wt,
    unsigned short* __restrict__ kb, unsigned short* __restrict__ qb,
    unsigned short* __restrict__ vT)
{
    __shared__ __align__(16) char As[2][8192];     // 64 rows x 128 B each

    const int tid = threadIdx.x, w = tid >> 6, lane = tid & 63;
    const int l31 = lane & 31, h = lane >> 5;
    const int wm = w >> 2, wn = w & 3;             // 2m x 4n wave grid
    const int l = blockIdx.x;
    const int low3 = l & 7, rest = l >> 3;
    const int mtile = (rest / 3) * 8 + low3;
    const int nh    = rest % 3;
    const int m0 = mtile * 64;
    const int arow = tid >> 3, ac = tid & 7;       // A staging: 8 thr/row

    const float* asrc0 = x + (size_t)(m0 + arow) * NEMBD + ac * 8;
    const uint4* wtfb0 = (const uint4*)wt
                         + (size_t)(nh * 4 + wn) * 48 * 64 + lane;

    #pragma unroll 1
    for (int rep = 0; rep < 3; ++rep) {
        // launder base pointers: block CSE of loads across reps
        const float* asrc = asrc0;
        const uint4* wtfb = wtfb0;
        asm volatile("" : "+v"(asrc), "+v"(wtfb));

        floatx16 acc;
        #pragma unroll
        for (int i = 0; i < 16; ++i) acc[i] = 0.f;

        // ---- prologue: B(0) frags, pack A(0), x(1) prefetch ----
        uint4 bq[2][4];
        #pragma unroll
        for (int ks = 0; ks < 4; ++ks) bq[0][ks] = wtfb[ks * 64];
        float4 a0 = ((const float4*)asrc)[0];
        float4 a1 = ((const float4*)asrc)[1];
        {
            uint4 u0 = make_uint4(pack2(a0.x, a0.y), pack2(a0.z, a0.w),
                                  pack2(a1.x, a1.y), pack2(a1.z, a1.w));
            *(uint4*)(As[0] + arow * 128 + ((ac ^ (arow & 7)) * 16)) = u0;
        }
        {
            const float4* src = (const float4*)(asrc + 64);
            a0 = src[0]; a1 = src[1];               // x(1), stays in flight
        }
        asm volatile("s_waitcnt lgkmcnt(0)" ::: "memory");
        __builtin_amdgcn_sched_barrier(0);
        __builtin_amdgcn_s_barrier();

        #pragma unroll
        for (int it = 0; it < 12; ++it) {
            char* Acur = As[it & 1];
            char* Anxt = As[(it & 1) ^ 1];

            if (it < 11) {
                #pragma unroll
                for (int ks = 0; ks < 4; ++ks)
                    bq[(it + 1) & 1][ks] = wtfb[((it + 1) * 4 + ks) * 64];
                uint4 u0 = make_uint4(pack2(a0.x, a0.y), pack2(a0.z, a0.w),
                                      pack2(a1.x, a1.y), pack2(a1.z, a1.w));
                *(uint4*)(Anxt + arow * 128 + ((ac ^ (arow & 7)) * 16)) = u0;
                if (it < 10) {
                    const float4* src = (const float4*)(asrc + (it + 2) * 64);
                    a0 = src[0]; a1 = src[1];
                }
            }

            const int ar = wm * 32 + l31;
            #pragma unroll
            for (int ks = 0; ks < 4; ++ks) {
                short8 af = *(const short8*)(Acur + ar * 128
                                             + (((2 * ks + h) ^ (ar & 7)) * 16));
                union { uint4 q; short8 v; } bb; bb.q = bq[it & 1][ks];
                acc = MFMA32(af, bb.v, acc);
            }

            if (it < 11) {
                asm volatile("s_waitcnt lgkmcnt(0)" ::: "memory");
                __builtin_amdgcn_sched_barrier(0);
                __builtin_amdgcn_s_barrier();
            }
        }

        // ---- epilogue: this block's matrix (nh) ----
        const int tbase = m0 + wm * 32;
        const int n0loc = wn * 32;                 // 0..96 within this matrix
        if (nh < 2) {
            unsigned short* outp = (nh == 0) ? kb : qb;
            int d = n0loc + l31;
            #pragma unroll
            for (int r = 0; r < 16; ++r) {
                int t = tbase + (r & 3) + 8 * (r >> 2) + 4 * h;
                outp[(size_t)t * HDIM + d] = f2bf(acc[r]);
            }
        } else {
            int d = n0loc + l31, b = m0 >> 10, tloc = (m0 & 1023) + wm * 32;
            #pragma unroll
            for (int g = 0; g < 4; ++g) {
                int t = tloc + 8 * g + 4 * h;
                uint2 u = make_uint2(pack2(acc[4*g+0], acc[4*g+1]),
                                     pack2(acc[4*g+2], acc[4*g+3]));
                *(uint2*)((char*)vT + (((size_t)(b * HDIM + d)) * 1024 + t) * 2) = u;
            }
        }
        __syncthreads();   // rep boundary: protect As WAR across reps
    }
}

// ---------------------------------------------------------------------------
// Kernel 2: flash attention (R7 structure), body repeated x5 for measurement.
//   dur ~50-60us -> attn_real ~10-12 (near floor).
//   dur >=90us   -> attn is the hidden hog; optimize attn next.
// ---------------------------------------------------------------------------
__global__ __launch_bounds__(256) void attn_mfma(
    const unsigned short* __restrict__ qb, const unsigned short* __restrict__ kb,
    const unsigned short* __restrict__ vT, float* __restrict__ out)
{
    __shared__ __align__(16) float Obuf[4 * 32 * 128];   // 64 KB, per-wave
    __shared__ float lred[128];

    const int tid = threadIdx.x, w = tid >> 6, lane = tid & 63;
    const int l31 = lane & 31, h = lane >> 5;
    const int u  = blockIdx.x & 255;
    const int b  = u & 15, p = u >> 4;
    const int qt = (blockIdx.x >> 8) ? (31 - p) : p;

    const char* kb_b0 = (const char*)kb + (size_t)b * (1024 * 256);
    const char* qb_b0 = (const char*)qb + (size_t)b * (1024 * 256);
    const char* vT_b0 = (const char*)vT + (size_t)b * (HDIM * 2048);

    #pragma unroll 1
    for (int rep = 0; rep < 5; ++rep) {
        __syncthreads();   // rep boundary: protect Obuf WAR across reps
        const char* kb_b = kb_b0;
        const char* qb_b = qb_b0;
        const char* vT_b = vT_b0;
        asm volatile("" : "+v"(kb_b), "+v"(qb_b), "+v"(vT_b));

        short8 qf[8];
        {
            const char* qrow = qb_b + (size_t)(qt * 32 + l31) * 256 + h * 16;
            #pragma unroll
            for (int ks = 0; ks < 8; ++ks)
                qf[ks] = *(const short8*)(qrow + ks * 32);
        }

        floatx16 o[4];
        #pragma unroll
        for (int nt = 0; nt < 4; ++nt)
            #pragma unroll
            for (int i = 0; i < 16; ++i) o[nt][i] = 0.f;
        float l_r = 0.f;

        short8 kf[8];
        if (w <= qt) {
            const char* krow = kb_b + (size_t)(w * 32 + l31) * 256 + h * 16;
            #pragma unroll
            for (int ks = 0; ks < 8; ++ks)
                kf[ks] = *(const short8*)(krow + ks * 32);
        }

        for (int st = w; st <= qt; st += 4) {
            short8 vf[8];
            {
                const char* vrow0 = vT_b + (size_t)l31 * 2048 + (size_t)st * 64 + h * 16;
                #pragma unroll
                for (int nt = 0; nt < 4; ++nt) {
                    const char* vr = vrow0 + (size_t)nt * (32 * 2048);
                    vf[nt * 2 + 0] = *(const short8*)(vr + 0);
                    vf[nt * 2 + 1] = *(const short8*)(vr + 32);
                }
            }
            floatx16 s;
            #pragma unroll
            for (int i = 0; i < 16; ++i) s[i] = 0.f;
            __builtin_amdgcn_s_setprio(1);
            #pragma unroll
            for (int ks = 0; ks < 8; ++ks) s = MFMA32(kf[ks], qf[ks], s);
            __builtin_amdgcn_s_setprio(0);

            if (st + 4 <= qt) {
                const char* krow = kb_b + (size_t)((st + 4) * 32 + l31) * 256 + h * 16;
                #pragma unroll
                for (int ks = 0; ks < 8; ++ks)
                    kf[ks] = *(const short8*)(krow + ks * 32);
            }

            if (st == qt) {            // causal mask on diagonal tile
                #pragma unroll
                for (int r = 0; r < 16; ++r) {
                    int key = (r & 3) + 8 * (r >> 2) + 4 * h;
                    if (key > l31) s[r] = -1e30f;
                }
            }
            float p16[16];
            float ps0 = 0.f, ps1 = 0.f, ps2 = 0.f, ps3 = 0.f;
            #pragma unroll
            for (int r = 0; r < 4; ++r) {
                p16[4*r+0] = __builtin_amdgcn_exp2f(s[4*r+0]);
                p16[4*r+1] = __builtin_amdgcn_exp2f(s[4*r+1]);
                p16[4*r+2] = __builtin_amdgcn_exp2f(s[4*r+2]);
                p16[4*r+3] = __builtin_amdgcn_exp2f(s[4*r+3]);
                ps0 += p16[4*r+0]; ps1 += p16[4*r+1];
                ps2 += p16[4*r+2]; ps3 += p16[4*r+3];
            }
            l_r += (ps0 + ps1) + (ps2 + ps3);

            unsigned own[8];
            #pragma unroll
            for (int i = 0; i < 8; ++i) own[i] = pack2_trunc(p16[2*i], p16[2*i+1]);
            asm("v_permlane32_swap_b32 %0, %1" : "+v"(own[0]), "+v"(own[2]));
            asm("v_permlane32_swap_b32 %0, %1" : "+v"(own[1]), "+v"(own[3]));
            asm("v_permlane32_swap_b32 %0, %1" : "+v"(own[4]), "+v"(own[6]));
            asm("v_permlane32_swap_b32 %0, %1" : "+v"(own[5]), "+v"(own[7]));
            short8 pf[2];
            {
                union { short8 v; unsigned uu[4]; } f0, f1;
                f0.uu[0]=own[0]; f0.uu[1]=own[1]; f0.uu[2]=own[2]; f0.uu[3]=own[3];
                f1.uu[0]=own[4]; f1.uu[1]=own[5]; f1.uu[2]=own[6]; f1.uu[3]=own[7];
                pf[0] = f0.v; pf[1] = f1.v;
            }
            __builtin_amdgcn_s_setprio(1);
            #pragma unroll
            for (int nt = 0; nt < 4; ++nt) {
                o[nt] = MFMA32(vf[nt * 2 + 0], pf[0], o[nt]);
                o[nt] = MFMA32(vf[nt * 2 + 1], pf[1], o[nt]);
            }
            __builtin_amdgcn_s_setprio(0);
        }

        // ---- merge: each wave -> private buffer, ONE barrier, parallel sum
        l_r += __shfl_xor(l_r, 32, 64);
        if (lane < 32) lred[w * 32 + l31] = l_r;
        {
            float* mybuf = &Obuf[w * 4096];
            #pragma unroll
            for (int nt = 0; nt < 4; ++nt) {
                #pragma unroll
                for (int g = 0; g < 4; ++g) {
                    int chunk = nt * 8 + 2 * g + h;
                    int slot  = (chunk & 24) | ((chunk & 7) ^ (l31 & 7));
                    *((float4*)&mybuf[l31 * 128] + slot) =
                        make_float4(o[nt][4*g+0], o[nt][4*g+1],
                                    o[nt][4*g+2], o[nt][4*g+3]);
                }
            }
        }
        __syncthreads();
        {
            int q  = tid >> 3;
            int cb = (tid & 7) * 4;
            float inv = 1.f / (lred[q] + lred[32 + q] + lred[64 + q] + lred[96 + q]);
            #pragma unroll
            for (int cc = 0; cc < 4; ++cc) {
                int chunk = cb + cc;
                int slot  = (chunk & 24) | ((chunk & 7) ^ (q & 7));
                float4 v0 = *((float4*)&Obuf[0 * 4096 + q * 128] + slot);
                float4 v1 = *((float4*)&Obuf[1 * 4096 + q * 128] + slot);
                float4 v2 = *((float4*)&Obuf[2 * 4096 + q * 128] + slot);
                float4 v3 = *((float4*)&Obuf[3 * 4096 + q * 128] + slot);
                float4 v = make_float4((v0.x + v1.x + v2.x + v3.x) * inv,
                                       (v0.y + v1.y + v2.y + v3.y) * inv,
                                       (v0.z + v1.z + v2.z + v3.z) * inv,
                                       (v0.w + v1.w + v2.w + v3.w) * inv);
                *(float4*)&out[((size_t)(b * 1024 + qt * 32 + q)) * HDIM + chunk * 4] = v;
            }
        }
    }
}

// ---------------------------------------------------------------------------
extern "C" void kernel_launch(void* const* d_in, const int* in_sizes, int n_in,
                              void* d_out, int out_size, void* d_ws, size_t ws_size,
                              hipStream_t stream)
{
    const float* x  = (const float*)d_in[0];
    const float* Wk = (const float*)d_in[1];
    const float* Wq = (const float*)d_in[2];
    const float* Wv = (const float*)d_in[3];
    float* outp = (float*)d_out;

    char* ws = (char*)d_ws;
    unsigned short* wt = (unsigned short*)(ws);               //  589824 B
    unsigned short* kb = (unsigned short*)(ws + 589824);      // 4194304 B
    unsigned short* qb = (unsigned short*)(ws + 4784128);     // 4194304 B
    unsigned short* vT = (unsigned short*)(ws + 8978432);     // 4194304 B

    prep_w<<<72, 256, 0, stream>>>(Wk, Wq, Wv, wt);
    qkv_fused<<<768, 512, 0, stream>>>(x, wt, kb, qb, vT);
    attn_mfma<<<512, 256, 0, stream>>>(qb, kb, vT, outp);
}

// Round 9
// 132.349 us; speedup vs baseline: 1.8785x; 1.8785x over previous
//
#include <hip/hip_runtime.h>
#include <hip/hip_bf16.h>
#include <math.h>

// B=16, T=1024, C=768, H=128
#define NTOK   16384     // B*T
#define NEMBD  768
#define HDIM   128

typedef __attribute__((ext_vector_type(8)))  short short8;
typedef __attribute__((ext_vector_type(16))) float floatx16;

#define MFMA32(a,b,c) __builtin_amdgcn_mfma_f32_32x32x16_bf16(a,b,c,0,0,0)

__device__ __forceinline__ unsigned short f2bf(float f) {
    unsigned u = __float_as_uint(f);
    u += 0x7fff + ((u >> 16) & 1);          // RNE
    return (unsigned short)(u >> 16);
}
// RNE pack of 2 floats -> 2 bf16 (low = a, high = b). Scalar-cast form:
// compiler lowers to one v_cvt_pk_bf16_f32 AND can schedule it.
__device__ __forceinline__ unsigned pack2(float a, float b) {
    __hip_bfloat162 h2 = __float22bfloat162_rn(make_float2(a, b));
    union { __hip_bfloat162 h; unsigned u; } c; c.h = h2;
    return c.u;
}
// truncating bf16 pack: one v_perm_b32. D = [hi16(b) | hi16(a)]
__device__ __forceinline__ unsigned pack2_trunc(float a, float b) {
    return __builtin_amdgcn_perm(__float_as_uint(b), __float_as_uint(a),
                                 0x07060302u);
}

// ---------------------------------------------------------------------------
// Kernel 0: W -> bf16 in MFMA FRAGMENT ORDER. (UNCHANGED from R7.)
// ---------------------------------------------------------------------------
__global__ __launch_bounds__(256) void prep_w(
    const float* __restrict__ Wk, const float* __restrict__ Wq,
    const float* __restrict__ Wv, unsigned short* __restrict__ wt)
{
    __shared__ float T[64 * 65];               // [dloc][c], pad 65

    const int tid = threadIdx.x;
    const int bw  = blockIdx.x / 24;
    const int rem = blockIdx.x % 24;
    const int ct  = rem >> 1, dh = rem & 1;
    const int c0  = ct * 64;
    const float* W = (bw == 0) ? Wk : ((bw == 1) ? Wq : Wv);
    const float scale = (bw == 1)
        ? (0.03608439182435161f * 1.4426950408889634f) : 1.0f;

    #pragma unroll
    for (int pass = 0; pass < 4; ++pass) {
        int idx = pass * 256 + tid;            // 0..1023
        int c  = idx >> 4;                     // 0..63
        int d4 = idx & 15;                     // float4 idx within d-half
        float4 v = ((const float4*)W)[(size_t)(c0 + c) * 32 + dh * 16 + d4];
        v.x *= scale; v.y *= scale; v.z *= scale; v.w *= scale;
        T[(d4 * 4 + 0) * 65 + c] = v.x;
        T[(d4 * 4 + 1) * 65 + c] = v.y;
        T[(d4 * 4 + 2) * 65 + c] = v.z;
        T[(d4 * 4 + 3) * 65 + c] = v.w;
    }
    __syncthreads();

    #pragma unroll
    for (int pass = 0; pass < 2; ++pass) {
        int idx  = pass * 256 + tid;           // 0..511
        int dloc = idx >> 3;                   // 0..63
        int c8   = idx & 7;                    // 8-col chunk within c-tile
        const float* row = &T[dloc * 65 + c8 * 8];
        uint4 u = make_uint4(pack2(row[0], row[1]), pack2(row[2], row[3]),
                             pack2(row[4], row[5]), pack2(row[6], row[7]));
        int kc    = ct * 8 + c8;               // global 8-col chunk 0..95
        int ksl   = kc >> 1, hb = kc & 1;
        int dglob = dh * 64 + dloc;
        int nt    = dglob >> 5;
        int lanef = (dglob & 31) + 32 * hb;
        ((uint4*)wt)[(size_t)((bw * 4 + nt) * 48 + ksl) * 64 + lanef] = u;
    }
}

// ---------------------------------------------------------------------------
// Kernel 1: fused x-convert + 3-way GEMM, B direct from global (fragment-
// order wt, reg double-buffered), A-only LDS dbuf. (UNCHANGED from R7.)
// ---------------------------------------------------------------------------
__global__ __launch_bounds__(512) void qkv_fused(
    const float* __restrict__ x, const unsigned short* __restrict__ wt,
    unsigned short* __restrict__ kb, unsigned short* __restrict__ qb,
    unsigned short* __restrict__ vT)
{
    __shared__ __align__(16) char As[2][8192];     // 64 rows x 128 B each

    const int tid = threadIdx.x, w = tid >> 6, lane = tid & 63;
    const int l31 = lane & 31, h = lane >> 5;
    const int wm = w >> 2, wn = w & 3;             // 2m x 4n wave grid
    const int l = blockIdx.x;
    const int low3 = l & 7, rest = l >> 3;
    const int mtile = (rest / 3) * 8 + low3;
    const int nh    = rest % 3;
    const int m0 = mtile * 64;
    const int arow = tid >> 3, ac = tid & 7;       // A staging: 8 thr/row

    floatx16 acc;
    #pragma unroll
    for (int i = 0; i < 16; ++i) acc[i] = 0.f;

    const float* asrc = x + (size_t)(m0 + arow) * NEMBD + ac * 8;
    const uint4* wtfb = (const uint4*)wt
                        + (size_t)(nh * 4 + wn) * 48 * 64 + lane;

    // ---- prologue: B(0) frags, pack A(0), x(1) prefetch ----
    uint4 bq[2][4];
    #pragma unroll
    for (int ks = 0; ks < 4; ++ks) bq[0][ks] = wtfb[ks * 64];
    float4 a0 = ((const float4*)asrc)[0];
    float4 a1 = ((const float4*)asrc)[1];
    {
        uint4 u0 = make_uint4(pack2(a0.x, a0.y), pack2(a0.z, a0.w),
                              pack2(a1.x, a1.y), pack2(a1.z, a1.w));
        *(uint4*)(As[0] + arow * 128 + ((ac ^ (arow & 7)) * 16)) = u0;
    }
    {
        const float4* src = (const float4*)(asrc + 64);
        a0 = src[0]; a1 = src[1];               // x(1), stays in flight
    }
    asm volatile("s_waitcnt lgkmcnt(0)" ::: "memory");
    __builtin_amdgcn_sched_barrier(0);
    __builtin_amdgcn_s_barrier();

    #pragma unroll
    for (int it = 0; it < 12; ++it) {
        char* Acur = As[it & 1];
        char* Anxt = As[(it & 1) ^ 1];

        if (it < 11) {
            // ---- prefetch B(it+1) frags (L2; consumed next iter) ----
            #pragma unroll
            for (int ks = 0; ks < 4; ++ks)
                bq[(it + 1) & 1][ks] = wtfb[((it + 1) * 4 + ks) * 64];
            // ---- pack A(it+1) (auto-waits x(it+1), keeps B in flight) ----
            uint4 u0 = make_uint4(pack2(a0.x, a0.y), pack2(a0.z, a0.w),
                                  pack2(a1.x, a1.y), pack2(a1.z, a1.w));
            *(uint4*)(Anxt + arow * 128 + ((ac ^ (arow & 7)) * 16)) = u0;
            // ---- issue x(it+2) loads ----
            if (it < 10) {
                const float4* src = (const float4*)(asrc + (it + 2) * 64);
                a0 = src[0]; a1 = src[1];
            }
        }

        // ---- MFMA: A frags from LDS, B frags from regs ----
        const int ar = wm * 32 + l31;
        #pragma unroll
        for (int ks = 0; ks < 4; ++ks) {
            short8 af = *(const short8*)(Acur + ar * 128
                                         + (((2 * ks + h) ^ (ar & 7)) * 16));
            union { uint4 q; short8 v; } bb; bb.q = bq[it & 1][ks];
            acc = MFMA32(af, bb.v, acc);
        }

        // ---- barrier: LDS visibility only, VMEM stays in flight ----
        if (it < 11) {
            asm volatile("s_waitcnt lgkmcnt(0)" ::: "memory");
            __builtin_amdgcn_sched_barrier(0);
            __builtin_amdgcn_s_barrier();
        }
    }

    // ---- epilogue: this block's matrix (nh) ----
    const int tbase = m0 + wm * 32;
    const int n0loc = wn * 32;                 // 0..96 within this matrix
    if (nh < 2) {
        unsigned short* outp = (nh == 0) ? kb : qb;
        int d = n0loc + l31;
        #pragma unroll
        for (int r = 0; r < 16; ++r) {
            int t = tbase + (r & 3) + 8 * (r >> 2) + 4 * h;
            outp[(size_t)t * HDIM + d] = f2bf(acc[r]);
        }
    } else {
        int d = n0loc + l31, b = m0 >> 10, tloc = (m0 & 1023) + wm * 32;
        #pragma unroll
        for (int g = 0; g < 4; ++g) {
            int t = tloc + 8 * g + 4 * h;
            uint2 u = make_uint2(pack2(acc[4*g+0], acc[4*g+1]),
                                 pack2(acc[4*g+2], acc[4*g+3]));
            *(uint2*)((char*)vT + (((size_t)(b * HDIM + d)) * 1024 + t) * 2) = u;
        }
    }
}

// ---------------------------------------------------------------------------
// Kernel 2: flash attention, 512 THREADS / 8 WAVES per block (R8 counters:
// MfmaUtil 8.3%, VALU 13.6%, HBM 3.3%, occupancy 16% -> latency-bound at
// 2 waves/SIMD; grid 512 x 4 waves was the cap). Waves stride K/V tiles
// by 8; resident waves/CU 8 -> 16 (4/SIMD, VGPR-120-feasible).
// Merge is TWO HALF-WIDTH passes (o[0..1] cols 0-63, then o[2..3]) so
// Obuf = 8 x 32 x 64 f32 = 64 KB keeps 2 blocks/CU.
// ---------------------------------------------------------------------------
__global__ __launch_bounds__(512) void attn_mfma(
    const unsigned short* __restrict__ qb, const unsigned short* __restrict__ kb,
    const unsigned short* __restrict__ vT, float* __restrict__ out)
{
    __shared__ __align__(16) float Obuf[8 * 32 * 64];    // 64 KB, per-wave half
    __shared__ float lred[256];

    const int tid = threadIdx.x, w = tid >> 6, lane = tid & 63;
    const int l31 = lane & 31, h = lane >> 5;
    const int u  = blockIdx.x & 255;
    const int b  = u & 15, p = u >> 4;
    const int qt = (blockIdx.x >> 8) ? (31 - p) : p;

    const char* kb_b = (const char*)kb + (size_t)b * (1024 * 256);
    const char* qb_b = (const char*)qb + (size_t)b * (1024 * 256);
    const char* vT_b = (const char*)vT + (size_t)b * (HDIM * 2048);

    short8 qf[8];
    {
        const char* qrow = qb_b + (size_t)(qt * 32 + l31) * 256 + h * 16;
        #pragma unroll
        for (int ks = 0; ks < 8; ++ks)
            qf[ks] = *(const short8*)(qrow + ks * 32);
    }

    floatx16 o[4];
    #pragma unroll
    for (int nt = 0; nt < 4; ++nt)
        #pragma unroll
        for (int i = 0; i < 16; ++i) o[nt][i] = 0.f;
    float l_r = 0.f;

    short8 kf[8];
    if (w <= qt) {
        const char* krow = kb_b + (size_t)(w * 32 + l31) * 256 + h * 16;
        #pragma unroll
        for (int ks = 0; ks < 8; ++ks)
            kf[ks] = *(const short8*)(krow + ks * 32);
    }

    for (int st = w; st <= qt; st += 8) {
        // ---- V loads first (independent of S chain) ----
        short8 vf[8];
        {
            const char* vrow0 = vT_b + (size_t)l31 * 2048 + (size_t)st * 64 + h * 16;
            #pragma unroll
            for (int nt = 0; nt < 4; ++nt) {
                const char* vr = vrow0 + (size_t)nt * (32 * 2048);
                vf[nt * 2 + 0] = *(const short8*)(vr + 0);
                vf[nt * 2 + 1] = *(const short8*)(vr + 32);
            }
        }
        // ---- S^T = K * Q^T  (log2e already in Q) ----
        floatx16 s;
        #pragma unroll
        for (int i = 0; i < 16; ++i) s[i] = 0.f;
        __builtin_amdgcn_s_setprio(1);
        #pragma unroll
        for (int ks = 0; ks < 8; ++ks) s = MFMA32(kf[ks], qf[ks], s);
        __builtin_amdgcn_s_setprio(0);

        // ---- prefetch next K tile ----
        if (st + 8 <= qt) {
            const char* krow = kb_b + (size_t)((st + 8) * 32 + l31) * 256 + h * 16;
            #pragma unroll
            for (int ks = 0; ks < 8; ++ks)
                kf[ks] = *(const short8*)(krow + ks * 32);
        }

        if (st == qt) {            // causal mask on diagonal tile
            #pragma unroll
            for (int r = 0; r < 16; ++r) {
                int key = (r & 3) + 8 * (r >> 2) + 4 * h;
                if (key > l31) s[r] = -1e30f;
            }
        }
        // ---- softmax numerator, fixed m=0: p = 2^s ----
        float p16[16];
        float ps0 = 0.f, ps1 = 0.f, ps2 = 0.f, ps3 = 0.f;
        #pragma unroll
        for (int r = 0; r < 4; ++r) {
            p16[4*r+0] = __builtin_amdgcn_exp2f(s[4*r+0]);
            p16[4*r+1] = __builtin_amdgcn_exp2f(s[4*r+1]);
            p16[4*r+2] = __builtin_amdgcn_exp2f(s[4*r+2]);
            p16[4*r+3] = __builtin_amdgcn_exp2f(s[4*r+3]);
            ps0 += p16[4*r+0]; ps1 += p16[4*r+1];
            ps2 += p16[4*r+2]; ps3 += p16[4*r+3];
        }
        l_r += (ps0 + ps1) + (ps2 + ps3);

        // ---- P^T -> B-operand frags via row-swap (no LDS, no divergence) --
        unsigned own[8];
        #pragma unroll
        for (int i = 0; i < 8; ++i) own[i] = pack2_trunc(p16[2*i], p16[2*i+1]);
        asm("v_permlane32_swap_b32 %0, %1" : "+v"(own[0]), "+v"(own[2]));
        asm("v_permlane32_swap_b32 %0, %1" : "+v"(own[1]), "+v"(own[3]));
        asm("v_permlane32_swap_b32 %0, %1" : "+v"(own[4]), "+v"(own[6]));
        asm("v_permlane32_swap_b32 %0, %1" : "+v"(own[5]), "+v"(own[7]));
        short8 pf[2];
        {
            union { short8 v; unsigned uu[4]; } f0, f1;
            f0.uu[0]=own[0]; f0.uu[1]=own[1]; f0.uu[2]=own[2]; f0.uu[3]=own[3];
            f1.uu[0]=own[4]; f1.uu[1]=own[5]; f1.uu[2]=own[6]; f1.uu[3]=own[7];
            pf[0] = f0.v; pf[1] = f1.v;
        }
        // ---- O^T += V^T * P^T ----
        __builtin_amdgcn_s_setprio(1);
        #pragma unroll
        for (int nt = 0; nt < 4; ++nt) {
            o[nt] = MFMA32(vf[nt * 2 + 0], pf[0], o[nt]);
            o[nt] = MFMA32(vf[nt * 2 + 1], pf[1], o[nt]);
        }
        __builtin_amdgcn_s_setprio(0);
    }

    // ---- merge: two half-width passes over 8 wave-buffers ----
    l_r += __shfl_xor(l_r, 32, 64);
    if (lane < 32) lred[w * 32 + l31] = l_r;

    const int q  = tid >> 4;          // 0..31 (reduce role)
    const int c4 = tid & 15;          // 0..15 float4-chunk within half
    const int rslot = (c4 & 8) | ((c4 & 7) ^ (q & 7));
    float inv;

    // ---- pass A: o[0], o[1] -> cols 0..63 ----
    {
        float* mybuf = &Obuf[w * 2048];
        #pragma unroll
        for (int ntp = 0; ntp < 2; ++ntp) {
            #pragma unroll
            for (int g = 0; g < 4; ++g) {
                int chunk = ntp * 8 + 2 * g + h;          // 0..15
                int slot  = (chunk & 8) | ((chunk & 7) ^ (l31 & 7));
                *((float4*)&mybuf[l31 * 64] + slot) =
                    make_float4(o[ntp][4*g+0], o[ntp][4*g+1],
                                o[ntp][4*g+2], o[ntp][4*g+3]);
            }
        }
    }
    __syncthreads();
    {
        inv = 1.f / (((lred[q]       + lred[32 + q]) + (lred[64 + q] + lred[96 + q]))
                   + ((lred[128 + q] + lred[160 + q]) + (lred[192 + q] + lred[224 + q])));
        float4 a = make_float4(0.f, 0.f, 0.f, 0.f);
        #pragma unroll
        for (int w8 = 0; w8 < 8; ++w8) {
            float4 v = *((float4*)&Obuf[w8 * 2048 + q * 64] + rslot);
            a.x += v.x; a.y += v.y; a.z += v.z; a.w += v.w;
        }
        a.x *= inv; a.y *= inv; a.z *= inv; a.w *= inv;
        *(float4*)&out[((size_t)(b * 1024 + qt * 32 + q)) * HDIM + c4 * 4] = a;
    }
    __syncthreads();

    // ---- pass B: o[2], o[3] -> cols 64..127 ----
    {
        float* mybuf = &Obuf[w * 2048];
        #pragma unroll
        for (int ntp = 0; ntp < 2; ++ntp) {
            #pragma unroll
            for (int g = 0; g < 4; ++g) {
                int chunk = ntp * 8 + 2 * g + h;          // 0..15
                int slot  = (chunk & 8) | ((chunk & 7) ^ (l31 & 7));
                *((float4*)&mybuf[l31 * 64] + slot) =
                    make_float4(o[2 + ntp][4*g+0], o[2 + ntp][4*g+1],
                                o[2 + ntp][4*g+2], o[2 + ntp][4*g+3]);
            }
        }
    }
    __syncthreads();
    {
        float4 a = make_float4(0.f, 0.f, 0.f, 0.f);
        #pragma unroll
        for (int w8 = 0; w8 < 8; ++w8) {
            float4 v = *((float4*)&Obuf[w8 * 2048 + q * 64] + rslot);
            a.x += v.x; a.y += v.y; a.z += v.z; a.w += v.w;
        }
        a.x *= inv; a.y *= inv; a.z *= inv; a.w *= inv;
        *(float4*)&out[((size_t)(b * 1024 + qt * 32 + q)) * HDIM + 64 + c4 * 4] = a;
    }
}

// ---------------------------------------------------------------------------
extern "C" void kernel_launch(void* const* d_in, const int* in_sizes, int n_in,
                              void* d_out, int out_size, void* d_ws, size_t ws_size,
                              hipStream_t stream)
{
    const float* x  = (const float*)d_in[0];
    const float* Wk = (const float*)d_in[1];
    const float* Wq = (const float*)d_in[2];
    const float* Wv = (const float*)d_in[3];
    float* outp = (float*)d_out;

    char* ws = (char*)d_ws;
    unsigned short* wt = (unsigned short*)(ws);               //  589824 B
    unsigned short* kb = (unsigned short*)(ws + 589824);      // 4194304 B
    unsigned short* qb = (unsigned short*)(ws + 4784128);     // 4194304 B
    unsigned short* vT = (unsigned short*)(ws + 8978432);     // 4194304 B

    prep_w<<<72, 256, 0, stream>>>(Wk, Wq, Wv, wt);
    qkv_fused<<<768, 512, 0, stream>>>(x, wt, kb, qb, vT);
    attn_mfma<<<512, 512, 0, stream>>>(qb, kb, vT, outp);
}

// Round 10
// 118.828 us; speedup vs baseline: 2.0922x; 1.1138x over previous
//
#include <hip/hip_runtime.h>
#include <hip/hip_bf16.h>
#include <math.h>

// B=16, T=1024, C=768, H=128
#define NTOK   16384     // B*T
#define NEMBD  768
#define HDIM   128

typedef __attribute__((ext_vector_type(8)))  short short8;
typedef __attribute__((ext_vector_type(16))) float floatx16;

#define MFMA32(a,b,c) __builtin_amdgcn_mfma_f32_32x32x16_bf16(a,b,c,0,0,0)

__device__ __forceinline__ unsigned short f2bf(float f) {
    unsigned u = __float_as_uint(f);
    u += 0x7fff + ((u >> 16) & 1);          // RNE
    return (unsigned short)(u >> 16);
}
// RNE pack of 2 floats -> 2 bf16 (low = a, high = b).
__device__ __forceinline__ unsigned pack2(float a, float b) {
    __hip_bfloat162 h2 = __float22bfloat162_rn(make_float2(a, b));
    union { __hip_bfloat162 h; unsigned u; } c; c.h = h2;
    return c.u;
}
// truncating bf16 pack: one v_perm_b32. D = [hi16(b) | hi16(a)]
__device__ __forceinline__ unsigned pack2_trunc(float a, float b) {
    return __builtin_amdgcn_perm(__float_as_uint(b), __float_as_uint(a),
                                 0x07060302u);
}

// ---------------------------------------------------------------------------
// Kernel 0: W -> bf16 in MFMA FRAGMENT ORDER. (UNCHANGED from R7.)
// wtf unit (16 B): [(bw*4 + nt)*48 + ksl]*64 + lane holds
// W[k = ksl*16 + (lane>>5)*8 + j][d = nt*32 + (lane&31)].
// ---------------------------------------------------------------------------
__global__ __launch_bounds__(256) void prep_w(
    const float* __restrict__ Wk, const float* __restrict__ Wq,
    const float* __restrict__ Wv, unsigned short* __restrict__ wt)
{
    __shared__ float T[64 * 65];               // [dloc][c], pad 65

    const int tid = threadIdx.x;
    const int bw  = blockIdx.x / 24;
    const int rem = blockIdx.x % 24;
    const int ct  = rem >> 1, dh = rem & 1;
    const int c0  = ct * 64;
    const float* W = (bw == 0) ? Wk : ((bw == 1) ? Wq : Wv);
    const float scale = (bw == 1)
        ? (0.03608439182435161f * 1.4426950408889634f) : 1.0f;

    #pragma unroll
    for (int pass = 0; pass < 4; ++pass) {
        int idx = pass * 256 + tid;            // 0..1023
        int c  = idx >> 4;                     // 0..63
        int d4 = idx & 15;                     // float4 idx within d-half
        float4 v = ((const float4*)W)[(size_t)(c0 + c) * 32 + dh * 16 + d4];
        v.x *= scale; v.y *= scale; v.z *= scale; v.w *= scale;
        T[(d4 * 4 + 0) * 65 + c] = v.x;
        T[(d4 * 4 + 1) * 65 + c] = v.y;
        T[(d4 * 4 + 2) * 65 + c] = v.z;
        T[(d4 * 4 + 3) * 65 + c] = v.w;
    }
    __syncthreads();

    #pragma unroll
    for (int pass = 0; pass < 2; ++pass) {
        int idx  = pass * 256 + tid;           // 0..511
        int dloc = idx >> 3;                   // 0..63
        int c8   = idx & 7;                    // 8-col chunk within c-tile
        const float* row = &T[dloc * 65 + c8 * 8];
        uint4 u = make_uint4(pack2(row[0], row[1]), pack2(row[2], row[3]),
                             pack2(row[4], row[5]), pack2(row[6], row[7]));
        int kc    = ct * 8 + c8;               // global 8-col chunk 0..95
        int ksl   = kc >> 1, hb = kc & 1;
        int dglob = dh * 64 + dloc;
        int nt    = dglob >> 5;
        int lanef = (dglob & 31) + 32 * hb;
        ((uint4*)wt)[(size_t)((bw * 4 + nt) * 48 + ksl) * 64 + lanef] = u;
    }
}

// ---------------------------------------------------------------------------
// Kernel 1: fused x-convert + 3-way GEMM (R7 loop), FRAGMENT-ORDER OUTPUTS.
// R8/R9 counters: attn is TA/transaction-bound (all pipes idle, HBM 3%,
// TLP null) because kb/qb/vT were consumed as 16B-per-lane at 256B/2048B
// lane stride. Fix: store kb/qb/vT in MFMA fragment order so both the
// stores here and the loads in attn are lane-contiguous (1 KB/wave/instr).
//  - kb/qb blocks compute acc = MFMA(bb, af)  -> acc rows = d, cols = t;
//    pairs + 4x v_permlane32_swap -> two coalesced uint4 stores.
//    kb/qb unit [(b*32+kt)*8 + ks]*64 + lane = K[kt*32+(l&31)]
//                                              [ks*16+(l>>5)*8 .. +8].
//  - vT block keeps acc = MFMA(af, bb) -> rows = t, cols = d; same swap;
//    vT unit [((b*32+st)*4+nt)*2+q]*64+lane = V[st*32+q*16+(l>>5)*8+j]
//                                              [nt*32+(l&31)].
// ---------------------------------------------------------------------------
__global__ __launch_bounds__(512) void qkv_fused(
    const float* __restrict__ x, const unsigned short* __restrict__ wt,
    unsigned short* __restrict__ kb, unsigned short* __restrict__ qb,
    unsigned short* __restrict__ vT)
{
    __shared__ __align__(16) char As[2][8192];     // 64 rows x 128 B each

    const int tid = threadIdx.x, w = tid >> 6, lane = tid & 63;
    const int l31 = lane & 31, h = lane >> 5;
    const int wm = w >> 2, wn = w & 3;             // 2m x 4n wave grid
    const int l = blockIdx.x;
    const int low3 = l & 7, rest = l >> 3;
    const int mtile = (rest / 3) * 8 + low3;
    const int nh    = rest % 3;
    const int m0 = mtile * 64;
    const int arow = tid >> 3, ac = tid & 7;       // A staging: 8 thr/row

    floatx16 acc;
    #pragma unroll
    for (int i = 0; i < 16; ++i) acc[i] = 0.f;

    const float* asrc = x + (size_t)(m0 + arow) * NEMBD + ac * 8;
    const uint4* wtfb = (const uint4*)wt
                        + (size_t)(nh * 4 + wn) * 48 * 64 + lane;

    // ---- prologue: B(0) frags, pack A(0), x(1) prefetch ----
    uint4 bq[2][4];
    #pragma unroll
    for (int ks = 0; ks < 4; ++ks) bq[0][ks] = wtfb[ks * 64];
    float4 a0 = ((const float4*)asrc)[0];
    float4 a1 = ((const float4*)asrc)[1];
    {
        uint4 u0 = make_uint4(pack2(a0.x, a0.y), pack2(a0.z, a0.w),
                              pack2(a1.x, a1.y), pack2(a1.z, a1.w));
        *(uint4*)(As[0] + arow * 128 + ((ac ^ (arow & 7)) * 16)) = u0;
    }
    {
        const float4* src = (const float4*)(asrc + 64);
        a0 = src[0]; a1 = src[1];               // x(1), stays in flight
    }
    asm volatile("s_waitcnt lgkmcnt(0)" ::: "memory");
    __builtin_amdgcn_sched_barrier(0);
    __builtin_amdgcn_s_barrier();

    #pragma unroll
    for (int it = 0; it < 12; ++it) {
        char* Acur = As[it & 1];
        char* Anxt = As[(it & 1) ^ 1];

        if (it < 11) {
            #pragma unroll
            for (int ks = 0; ks < 4; ++ks)
                bq[(it + 1) & 1][ks] = wtfb[((it + 1) * 4 + ks) * 64];
            uint4 u0 = make_uint4(pack2(a0.x, a0.y), pack2(a0.z, a0.w),
                                  pack2(a1.x, a1.y), pack2(a1.z, a1.w));
            *(uint4*)(Anxt + arow * 128 + ((ac ^ (arow & 7)) * 16)) = u0;
            if (it < 10) {
                const float4* src = (const float4*)(asrc + (it + 2) * 64);
                a0 = src[0]; a1 = src[1];
            }
        }

        // ---- MFMA: kb/qb swapped operands (acc = C^T), vT unswapped ----
        const int ar = wm * 32 + l31;
        #pragma unroll
        for (int ks = 0; ks < 4; ++ks) {
            short8 af = *(const short8*)(Acur + ar * 128
                                         + (((2 * ks + h) ^ (ar & 7)) * 16));
            union { uint4 q; short8 v; } bb; bb.q = bq[it & 1][ks];
            if (nh < 2) acc = MFMA32(bb.v, af, acc);
            else        acc = MFMA32(af, bb.v, acc);
        }

        if (it < 11) {
            asm volatile("s_waitcnt lgkmcnt(0)" ::: "memory");
            __builtin_amdgcn_sched_barrier(0);
            __builtin_amdgcn_s_barrier();
        }
    }

    // ---- epilogue: pairs + cross-half swap -> 2 coalesced 16B stores ----
    const int bidx = m0 >> 10;
    const int ktl  = ((m0 & 1023) >> 5) + wm;      // t-tile within batch
    unsigned own[8];
    #pragma unroll
    for (int i = 0; i < 8; ++i) own[i] = pack2(acc[2*i], acc[2*i+1]);
    asm("v_permlane32_swap_b32 %0, %1" : "+v"(own[0]), "+v"(own[2]));
    asm("v_permlane32_swap_b32 %0, %1" : "+v"(own[1]), "+v"(own[3]));
    asm("v_permlane32_swap_b32 %0, %1" : "+v"(own[4]), "+v"(own[6]));
    asm("v_permlane32_swap_b32 %0, %1" : "+v"(own[5]), "+v"(own[7]));
    uint4 u1 = make_uint4(own[0], own[1], own[2], own[3]);
    uint4 u2 = make_uint4(own[4], own[5], own[6], own[7]);
    if (nh < 2) {
        uint4* outp = (uint4*)((nh == 0) ? kb : qb);
        size_t base = ((size_t)(bidx * 32 + ktl) * 8 + 2 * wn) * 64 + lane;
        outp[base]      = u1;      // ks = 2wn   (d-offs 0..15 across halves)
        outp[base + 64] = u2;      // ks = 2wn+1 (d-offs 16..31)
    } else {
        uint4* outp = (uint4*)vT;
        size_t base = ((size_t)(bidx * 32 + ktl) * 4 + wn) * 2 * 64 + lane;
        outp[base]      = u1;      // q = 0 (t-offs 0..15)
        outp[base + 64] = u2;      // q = 1 (t-offs 16..31)
    }
}

// ---------------------------------------------------------------------------
// Kernel 2: flash attention (R7 4-wave form), FRAGMENT-ORDER LOADS.
// All K/Q/V loads are now lane-contiguous global_load_dwordx4 (was 16B/lane
// at 256B/2048B stride = 64 lines/instr -> TA-bound, the R8-measured wall).
// ---------------------------------------------------------------------------
__global__ __launch_bounds__(256) void attn_mfma(
    const unsigned short* __restrict__ qb, const unsigned short* __restrict__ kb,
    const unsigned short* __restrict__ vT, float* __restrict__ out)
{
    __shared__ __align__(16) float Obuf[4 * 32 * 128];   // 64 KB, per-wave
    __shared__ float lred[128];

    const int tid = threadIdx.x, w = tid >> 6, lane = tid & 63;
    const int l31 = lane & 31, h = lane >> 5;
    const int u  = blockIdx.x & 255;
    const int b  = u & 15, p = u >> 4;
    const int qt = (blockIdx.x >> 8) ? (31 - p) : p;

    // fragment-unit pointers (uint4 = 16 B unit), 16384 units per batch
    const uint4* qbu = (const uint4*)qb + (size_t)b * 16384 + lane;
    const uint4* kbu = (const uint4*)kb + (size_t)b * 16384 + lane;
    const uint4* vtu = (const uint4*)vT + (size_t)b * 16384 + lane;

    short8 qf[8];
    #pragma unroll
    for (int ks = 0; ks < 8; ++ks)
        qf[ks] = *(const short8*)(qbu + ((size_t)qt * 8 + ks) * 64);

    floatx16 o[4];
    #pragma unroll
    for (int nt = 0; nt < 4; ++nt)
        #pragma unroll
        for (int i = 0; i < 16; ++i) o[nt][i] = 0.f;
    float l_r = 0.f;

    short8 kf[8];
    if (w <= qt) {
        #pragma unroll
        for (int ks = 0; ks < 8; ++ks)
            kf[ks] = *(const short8*)(kbu + ((size_t)w * 8 + ks) * 64);
    }

    for (int st = w; st <= qt; st += 4) {
        // ---- V loads first (independent of S chain), coalesced ----
        short8 vf[8];
        #pragma unroll
        for (int nt = 0; nt < 4; ++nt) {
            vf[nt * 2 + 0] = *(const short8*)(vtu + (((size_t)st * 4 + nt) * 2 + 0) * 64);
            vf[nt * 2 + 1] = *(const short8*)(vtu + (((size_t)st * 4 + nt) * 2 + 1) * 64);
        }
        // ---- S^T = K * Q^T  (log2e already in Q) ----
        floatx16 s;
        #pragma unroll
        for (int i = 0; i < 16; ++i) s[i] = 0.f;
        __builtin_amdgcn_s_setprio(1);
        #pragma unroll
        for (int ks = 0; ks < 8; ++ks) s = MFMA32(kf[ks], qf[ks], s);
        __builtin_amdgcn_s_setprio(0);

        // ---- prefetch next K tile (coalesced) ----
        if (st + 4 <= qt) {
            #pragma unroll
            for (int ks = 0; ks < 8; ++ks)
                kf[ks] = *(const short8*)(kbu + ((size_t)(st + 4) * 8 + ks) * 64);
        }

        if (st == qt) {            // causal mask on diagonal tile
            #pragma unroll
            for (int r = 0; r < 16; ++r) {
                int key = (r & 3) + 8 * (r >> 2) + 4 * h;
                if (key > l31) s[r] = -1e30f;
            }
        }
        // ---- softmax numerator, fixed m=0: p = 2^s ----
        float p16[16];
        float ps0 = 0.f, ps1 = 0.f, ps2 = 0.f, ps3 = 0.f;
        #pragma unroll
        for (int r = 0; r < 4; ++r) {
            p16[4*r+0] = __builtin_amdgcn_exp2f(s[4*r+0]);
            p16[4*r+1] = __builtin_amdgcn_exp2f(s[4*r+1]);
            p16[4*r+2] = __builtin_amdgcn_exp2f(s[4*r+2]);
            p16[4*r+3] = __builtin_amdgcn_exp2f(s[4*r+3]);
            ps0 += p16[4*r+0]; ps1 += p16[4*r+1];
            ps2 += p16[4*r+2]; ps3 += p16[4*r+3];
        }
        l_r += (ps0 + ps1) + (ps2 + ps3);

        // ---- P^T -> B-operand frags via row-swap ----
        unsigned own[8];
        #pragma unroll
        for (int i = 0; i < 8; ++i) own[i] = pack2_trunc(p16[2*i], p16[2*i+1]);
        asm("v_permlane32_swap_b32 %0, %1" : "+v"(own[0]), "+v"(own[2]));
        asm("v_permlane32_swap_b32 %0, %1" : "+v"(own[1]), "+v"(own[3]));
        asm("v_permlane32_swap_b32 %0, %1" : "+v"(own[4]), "+v"(own[6]));
        asm("v_permlane32_swap_b32 %0, %1" : "+v"(own[5]), "+v"(own[7]));
        short8 pf[2];
        {
            union { short8 v; unsigned uu[4]; } f0, f1;
            f0.uu[0]=own[0]; f0.uu[1]=own[1]; f0.uu[2]=own[2]; f0.uu[3]=own[3];
            f1.uu[0]=own[4]; f1.uu[1]=own[5]; f1.uu[2]=own[6]; f1.uu[3]=own[7];
            pf[0] = f0.v; pf[1] = f1.v;
        }
        // ---- O^T += V^T * P^T ----
        __builtin_amdgcn_s_setprio(1);
        #pragma unroll
        for (int nt = 0; nt < 4; ++nt) {
            o[nt] = MFMA32(vf[nt * 2 + 0], pf[0], o[nt]);
            o[nt] = MFMA32(vf[nt * 2 + 1], pf[1], o[nt]);
        }
        __builtin_amdgcn_s_setprio(0);
    }

    // ---- merge: each wave -> private buffer, ONE barrier, parallel sum ----
    l_r += __shfl_xor(l_r, 32, 64);
    if (lane < 32) lred[w * 32 + l31] = l_r;
    {
        float* mybuf = &Obuf[w * 4096];
        #pragma unroll
        for (int nt = 0; nt < 4; ++nt) {
            #pragma unroll
            for (int g = 0; g < 4; ++g) {
                int chunk = nt * 8 + 2 * g + h;
                int slot  = (chunk & 24) | ((chunk & 7) ^ (l31 & 7));
                *((float4*)&mybuf[l31 * 128] + slot) =
                    make_float4(o[nt][4*g+0], o[nt][4*g+1],
                                o[nt][4*g+2], o[nt][4*g+3]);
            }
        }
    }
    __syncthreads();
    {
        int q  = tid >> 3;
        int cb = (tid & 7) * 4;
        float inv = 1.f / (lred[q] + lred[32 + q] + lred[64 + q] + lred[96 + q]);
        #pragma unroll
        for (int cc = 0; cc < 4; ++cc) {
            int chunk = cb + cc;
            int slot  = (chunk & 24) | ((chunk & 7) ^ (q & 7));
            float4 v0 = *((float4*)&Obuf[0 * 4096 + q * 128] + slot);
            float4 v1 = *((float4*)&Obuf[1 * 4096 + q * 128] + slot);
            float4 v2 = *((float4*)&Obuf[2 * 4096 + q * 128] + slot);
            float4 v3 = *((float4*)&Obuf[3 * 4096 + q * 128] + slot);
            float4 v = make_float4((v0.x + v1.x + v2.x + v3.x) * inv,
                                   (v0.y + v1.y + v2.y + v3.y) * inv,
                                   (v0.z + v1.z + v2.z + v3.z) * inv,
                                   (v0.w + v1.w + v2.w + v3.w) * inv);
            *(float4*)&out[((size_t)(b * 1024 + qt * 32 + q)) * HDIM + chunk * 4] = v;
        }
    }
}

// ---------------------------------------------------------------------------
extern "C" void kernel_launch(void* const* d_in, const int* in_sizes, int n_in,
                              void* d_out, int out_size, void* d_ws, size_t ws_size,
                              hipStream_t stream)
{
    const float* x  = (const float*)d_in[0];
    const float* Wk = (const float*)d_in[1];
    const float* Wq = (const float*)d_in[2];
    const float* Wv = (const float*)d_in[3];
    float* outp = (float*)d_out;

    char* ws = (char*)d_ws;
    unsigned short* wt = (unsigned short*)(ws);               //  589824 B
    unsigned short* kb = (unsigned short*)(ws + 589824);      // 4194304 B
    unsigned short* qb = (unsigned short*)(ws + 4784128);     // 4194304 B
    unsigned short* vT = (unsigned short*)(ws + 8978432);     // 4194304 B

    prep_w<<<72, 256, 0, stream>>>(Wk, Wq, Wv, wt);
    qkv_fused<<<768, 512, 0, stream>>>(x, wt, kb, qb, vT);
    attn_mfma<<<512, 256, 0, stream>>>(qb, kb, vT, outp);
}